// Round 10
// baseline (842.535 us; speedup 1.0000x reference)
//
#include <hip/hip_runtime.h>
#include <hip/hip_bf16.h>

using bf16 = __hip_bfloat16;
typedef __attribute__((ext_vector_type(8))) short short8;
typedef __attribute__((ext_vector_type(4))) float floatx4;

#define NN 50000
#define EE 800000
#define DD 128
#define HH 8
#define CC 16
#define EDD 32
#define DF 512
#define NQC 64      // partitioned queue counters
#define PART 782    // ceil(NN/NQC)

__device__ __forceinline__ float bs2f(short s) {
    bf16 h = *reinterpret_cast<bf16*>(&s);
    return __bfloat162float(h);
}
__device__ __forceinline__ float bu2f(unsigned short s) {
    unsigned int u = ((unsigned int)s) << 16;
    return *reinterpret_cast<float*>(&u);
}
__device__ __forceinline__ short f2bs(float v) {
    bf16 h = __float2bfloat16(v);
    return *reinterpret_cast<short*>(&h);
}
__device__ __forceinline__ float asf(unsigned int u) {
    return *reinterpret_cast<float*>(&u);
}

__device__ __forceinline__ int clampn(int v)
{
    return (v < 0) ? 0 : (v >= NN ? NN - 1 : v);
}

// ---- pack fp32 weights [K][N] into per-lane MFMA B-frag layout (bf16) ----
// + zero deg/cursor/qcounter; + detect edge_index width (thread 196608)
__global__ void k_packall(const float* __restrict__ Wq, const float* __restrict__ Wk,
                          const float* __restrict__ Wv, const float* __restrict__ Wsk,
                          const float* __restrict__ W1, const float* __restrict__ W2,
                          bf16* __restrict__ wqp, bf16* __restrict__ wkp,
                          bf16* __restrict__ wvp, bf16* __restrict__ wskp,
                          bf16* __restrict__ w1p, bf16* __restrict__ w2p,
                          const int* __restrict__ ei, int* __restrict__ flag,
                          int* __restrict__ deg, int* __restrict__ cursor,
                          int* __restrict__ qcounter)
{
    int idx = blockIdx.x * 256 + threadIdx.x;
    if (idx < NN) deg[idx] = 0;
    else if (idx < 2 * NN) cursor[idx - NN] = 0;
    else if (idx < 2 * NN + NQC * 16) qcounter[idx - 2 * NN] = 0;

    const float* W; bf16* out; int ksteps, N, local;
    if (idx < 65536) {
        int wsel = idx >> 14; local = idx & 16383;
        W   = (wsel == 0) ? Wq  : (wsel == 1) ? Wk  : (wsel == 2) ? Wv  : Wsk;
        out = (wsel == 0) ? wqp : (wsel == 1) ? wkp : (wsel == 2) ? wvp : wskp;
        ksteps = 4; N = 128;
    } else if (idx < 131072) { local = idx - 65536;  W = W1; out = w1p; ksteps = 4;  N = 512; }
    else if (idx < 196608)   { local = idx - 131072; W = W2; out = w2p; ksteps = 16; N = 128; }
    else {
        if (idx == 196608) {
            int all0 = 1;
            for (int i = 0; i < 16; ++i) all0 &= (ei[2 * i + 1] == 0);
            flag[0] = all0;    // 1 => int64 layout, 0 => int32
        }
        return;
    }
    int j = local & 7, lane = (local >> 3) & 63, rest = local >> 9;
    int kstep = rest % ksteps, ntile = rest / ksteps;
    int quad = lane >> 4, m = lane & 15;
    int k = kstep * 32 + quad * 8 + j;
    int n = ntile * 16 + m;
    out[local] = __float2bfloat16(W[(size_t)k * N + n]);
}

// ---- WqW = Wq @ We2 (block-diag fold) -> MFMA B-frags; bqW = bq @ We2 ----
// WqW[r, h*32+d] = sum_c Wq[r, h*16+c] * We[d, h*16+c]
__global__ void k_wqw(const float* __restrict__ Wq, const float* __restrict__ We,
                      const float* __restrict__ bq,
                      bf16* __restrict__ wqwp, float* __restrict__ bqW)
{
    int idx = blockIdx.x * 256 + threadIdx.x;   // 128*256 = 32768
    int k = idx >> 8, n = idx & 255;
    int h = n >> 5, d = n & 31;
    const float* wq = Wq + (size_t)k * 128 + h * 16;
    const float* we = We + (size_t)d * 128 + h * 16;
    float v = 0.f;
#pragma unroll
    for (int c = 0; c < 16; ++c) v = fmaf(wq[c], we[c], v);
    int kstep = k >> 5, quad = (k >> 3) & 3, j = k & 7;
    int nt = n >> 4, m = n & 15;
    wqwp[(((nt * 4) + kstep) * 64 + quad * 16 + m) * 8 + j] = __float2bfloat16(v);
    if (k == 0) {
        const float* bqh = bq + h * 16;
        float bv = 0.f;
#pragma unroll
        for (int c = 0; c < 16; ++c) bv = fmaf(bqh[c], we[c], bv);
        bqW[n] = bv;
    }
}

// -------- projections via MFMA: q, kv packed (k hi | v lo), skip(+x), qW --------
__global__ __launch_bounds__(256) void k_proj(
    const float* __restrict__ x,
    const bf16* __restrict__ wqp, const bf16* __restrict__ wkp,
    const bf16* __restrict__ wvp, const bf16* __restrict__ wskp,
    const bf16* __restrict__ wqwp, const float* __restrict__ bqW,
    const float* __restrict__ bq, const float* __restrict__ bk,
    const float* __restrict__ bv, const float* __restrict__ bsk,
    bf16* __restrict__ qb, unsigned int* __restrict__ kvb,
    bf16* __restrict__ skipb, uint2* __restrict__ qWb)
{
    __shared__ __align__(16) short xs[32][136];
    __shared__ __align__(16) short os[32][520];
    short* osf = &os[0][0];
    const int t = threadIdx.x;
    const int wave = t >> 6, lane = t & 63;
    const int quad = lane >> 4, m = lane & 15;
    const int n0 = blockIdx.x * 32;

    for (int idx = t; idx < 32 * 32; idx += 256) {
        int row = idx >> 5, g = idx & 31;
        int node = n0 + row;
        float4 xv = {0.f, 0.f, 0.f, 0.f};
        if (node < NN) xv = *reinterpret_cast<const float4*>(&x[(size_t)node * 128 + g * 4]);
        short4 s4;
        s4.x = f2bs(xv.x); s4.y = f2bs(xv.y); s4.z = f2bs(xv.z); s4.w = f2bs(xv.w);
        *reinterpret_cast<short4*>(&xs[row][g * 4]) = s4;
    }
    __syncthreads();

    const bf16* Wp = (wave == 0) ? wqp : (wave == 1) ? wkp : (wave == 2) ? wvp : wskp;
    const float* bias = (wave == 0) ? bq : (wave == 1) ? bk : (wave == 2) ? bv : bsk;

    floatx4 acc[2][8];
#pragma unroll
    for (int mt = 0; mt < 2; ++mt)
#pragma unroll
        for (int nt = 0; nt < 8; ++nt) acc[mt][nt] = (floatx4){0.f, 0.f, 0.f, 0.f};

#pragma unroll
    for (int kstep = 0; kstep < 4; ++kstep) {
        short8 af0 = *reinterpret_cast<const short8*>(&xs[m][kstep * 32 + quad * 8]);
        short8 af1 = *reinterpret_cast<const short8*>(&xs[16 + m][kstep * 32 + quad * 8]);
#pragma unroll
        for (int nt = 0; nt < 8; ++nt) {
            short8 bf = *reinterpret_cast<const short8*>(
                reinterpret_cast<const short*>(Wp) + ((nt * 4 + kstep) * 64 + lane) * 8);
            acc[0][nt] = __builtin_amdgcn_mfma_f32_16x16x32_bf16(af0, bf, acc[0][nt], 0, 0, 0);
            acc[1][nt] = __builtin_amdgcn_mfma_f32_16x16x32_bf16(af1, bf, acc[1][nt], 0, 0, 0);
        }
    }
#pragma unroll
    for (int nt = 0; nt < 8; ++nt) {
        float bs = bias[nt * 16 + m];
#pragma unroll
        for (int mt = 0; mt < 2; ++mt)
#pragma unroll
            for (int r = 0; r < 4; ++r)
                os[mt * 16 + quad * 4 + r][wave * 128 + nt * 16 + m] = f2bs(acc[mt][nt][r] + bs);
    }
    __syncthreads();
    // q (u32 lo=even ch), skip+x, kv packed (k in HIGH half, v in LOW half)
    for (int idx = t; idx < 32 * 64; idx += 256) {
        int row = idx >> 6, c = idx & 63;
        int node = n0 + row;
        if (node >= NN) continue;
        unsigned int qu  = *reinterpret_cast<const unsigned int*>(&os[row][2 * c]);
        unsigned int ku  = *reinterpret_cast<const unsigned int*>(&os[row][128 + 2 * c]);
        unsigned int vu  = *reinterpret_cast<const unsigned int*>(&os[row][256 + 2 * c]);
        float sk0 = bs2f(os[row][384 + 2 * c])     + bs2f(xs[row][2 * c]);
        float sk1 = bs2f(os[row][384 + 2 * c + 1]) + bs2f(xs[row][2 * c + 1]);
        unsigned int sku = (unsigned int)(unsigned short)f2bs(sk0) |
                           ((unsigned int)(unsigned short)f2bs(sk1) << 16);
        reinterpret_cast<unsigned int*>(qb)[(size_t)node * 64 + c] = qu;
        reinterpret_cast<unsigned int*>(skipb)[(size_t)node * 64 + c] = sku;
        uint2 kv;
        kv.x = (vu & 0xffffu) | (ku << 16);          // ch 2c  : k hi, v lo
        kv.y = (vu >> 16) | (ku & 0xffff0000u);      // ch 2c+1: k hi, v lo
        reinterpret_cast<uint2*>(kvb)[(size_t)node * 64 + c] = kv;
    }
    __syncthreads();   // all consumers of os done

    // ---- pass 2: qW = x @ WqW + bqW (256 cols, 4 ntiles per wave) ----
    floatx4 acc2[2][4];
#pragma unroll
    for (int mt = 0; mt < 2; ++mt)
#pragma unroll
        for (int nt = 0; nt < 4; ++nt) acc2[mt][nt] = (floatx4){0.f, 0.f, 0.f, 0.f};
#pragma unroll
    for (int kstep = 0; kstep < 4; ++kstep) {
        short8 af0 = *reinterpret_cast<const short8*>(&xs[m][kstep * 32 + quad * 8]);
        short8 af1 = *reinterpret_cast<const short8*>(&xs[16 + m][kstep * 32 + quad * 8]);
#pragma unroll
        for (int nt = 0; nt < 4; ++nt) {
            short8 bf = *reinterpret_cast<const short8*>(
                reinterpret_cast<const short*>(wqwp) + (((wave * 4 + nt) * 4 + kstep) * 64 + lane) * 8);
            acc2[0][nt] = __builtin_amdgcn_mfma_f32_16x16x32_bf16(af0, bf, acc2[0][nt], 0, 0, 0);
            acc2[1][nt] = __builtin_amdgcn_mfma_f32_16x16x32_bf16(af1, bf, acc2[1][nt], 0, 0, 0);
        }
    }
#pragma unroll
    for (int nt = 0; nt < 4; ++nt) {
        int col = wave * 64 + nt * 16 + m;
        float bs = bqW[col];
#pragma unroll
        for (int mt = 0; mt < 2; ++mt)
#pragma unroll
            for (int r = 0; r < 4; ++r)
                osf[(mt * 16 + quad * 4 + r) * 256 + col] = f2bs(acc2[mt][nt][r] + bs);
    }
    __syncthreads();
    for (int idx = t; idx < 32 * 64; idx += 256) {
        int row = idx >> 6, c2 = idx & 63;
        int node = n0 + row;
        if (node >= NN) continue;
        qWb[(size_t)node * 64 + c2] = *reinterpret_cast<const uint2*>(&osf[row * 256 + c2 * 4]);
    }
}

// ---------------- CSR build ----------------
__global__ void k_hist(const int* __restrict__ ei, const int* __restrict__ flag,
                       int* __restrict__ deg)
{
    int tt = blockIdx.x * 256 + threadIdx.x;
    int i0 = tt * 2;
    if (i0 >= EE) return;
    int d0, d1;
    if (flag[0]) {
        int4 v = *reinterpret_cast<const int4*>(&ei[2 * EE + 2 * i0]);
        d0 = v.x; d1 = v.z;
    } else {
        int2 v = *reinterpret_cast<const int2*>(&ei[EE + i0]);
        d0 = v.x; d1 = v.y;
    }
    atomicAdd(&deg[clampn(d0)], 1);
    atomicAdd(&deg[clampn(d1)], 1);
}

__global__ __launch_bounds__(1024) void k_scan(const int* __restrict__ deg,
                                               int* __restrict__ rowstart)
{
    __shared__ int s[1024];
    const int t = threadIdx.x;
    const int CH = 49;
    int base = t * CH;
    int sum = 0;
    for (int i = 0; i < CH; i++) {
        int idx = base + i;
        if (idx < NN) sum += deg[idx];
    }
    s[t] = sum;
    __syncthreads();
    int own = sum;
    for (int off = 1; off < 1024; off <<= 1) {
        int v = (t >= off) ? s[t - off] : 0;
        __syncthreads();
        s[t] += v;
        __syncthreads();
    }
    int run = s[t] - own;
    for (int i = 0; i < CH; i++) {
        int idx = base + i;
        if (idx < NN) {
            rowstart[idx] = run;
            run += deg[idx];
        }
    }
    if (t == 0) rowstart[NN] = EE;
}

// scatter: permutation only — one scattered 8B store {src, eid} per edge
__global__ void k_scatter(const int* __restrict__ ei, const int* __restrict__ flag,
                          const int* __restrict__ rowstart,
                          int* __restrict__ cursor, int2* __restrict__ srcid)
{
    int i = blockIdx.x * 256 + threadIdx.x;
    if (i >= EE) return;
    int is64 = flag[0];
    int d = clampn(is64 ? ei[2 * EE + 2 * i] : ei[EE + i]);
    int s = clampn(is64 ? ei[2 * i] : ei[i]);
    int pos = rowstart[d] + atomicAdd(&cursor[d], 1);
    srcid[pos] = make_int2(s, i);
}

// -------- fused attention: NO MFMA — factored-e algebra, 64-VGPR budget --------
// alpha = q.k + ea.qW[dst];  PV e-part via wea accumulator resolved against We.
// 4-edge batches (kvr[4]+eav[4] = 24 buffer VGPRs) + srcid double-buffer prefetch
// keep the kernel under the 64-VGPR occupancy cliff (8 waves/SIMD).
__global__ __launch_bounds__(256, 8) void k_attn(
    const float* __restrict__ edge_attr, const float* __restrict__ We,
    const bf16* __restrict__ qb, const uint2* __restrict__ qWb,
    const unsigned int* __restrict__ kvb, const bf16* __restrict__ skipb,
    const int* __restrict__ rowstart, const int2* __restrict__ srcid,
    const float* __restrict__ ln1g, const float* __restrict__ ln1b,
    int* __restrict__ qcounter, bf16* __restrict__ hb)
{
    __shared__ float wes[32][128];   // We staged fp32 (16KB)
    const int t = threadIdx.x;
    const int wave = t >> 6, lane = t & 63;
    const int sub = lane & 7;

    for (int idx = t; idx < 1024; idx += 256)
        reinterpret_cast<float4*>(&wes[0][0])[idx] =
            reinterpret_cast<const float4*>(We)[idx];
    __syncthreads();   // only barrier in the kernel

    const float QS = 0.3606737602f;   // 0.25 * log2(e)
    const int gw = blockIdx.x * 4 + wave;
    const int c  = gw & (NQC - 1);
    const int base = c * PART;
    const int cnt_c = (NN - base < PART) ? (NN - base) : PART;
    int* qc = qcounter + c * 16;

    for (;;) {
        int nl;
        if (lane == 0) nl = atomicAdd(qc, 2);
        nl = __builtin_amdgcn_readfirstlane(nl);
        if (nl >= cnt_c) break;
        const int nhi = (nl + 2 < cnt_c) ? nl + 2 : cnt_c;

        for (int ni = nl; ni < nhi; ++ni) {
            const int n = base + ni;

            unsigned int qp = reinterpret_cast<const unsigned int*>(qb)[(size_t)n * 64 + lane];
            float q0 = asf(qp << 16) * QS;
            float q1 = asf(qp & 0xffff0000u) * QS;
            uint2 qwu = qWb[(size_t)n * 64 + lane];
            float qw0 = asf(qwu.x << 16) * QS;
            float qw1 = asf(qwu.x & 0xffff0000u) * QS;
            float qw2 = asf(qwu.y << 16) * QS;
            float qw3 = asf(qwu.y & 0xffff0000u) * QS;

            const int eoff = rowstart[n], eend = rowstart[n + 1];
            float lsum = 0.f, a0 = 0.f, a1 = 0.f;
            float wea0 = 0.f, wea1 = 0.f, wea2 = 0.f, wea3 = 0.f;

            int2 se;
            if (eoff < eend) {
                int pc0 = eoff + (lane & 3);
                se = srcid[(pc0 < eend) ? pc0 : eend - 1];
            }
            for (int p0 = eoff; p0 < eend; p0 += 4) {
                // prefetch NEXT tile's srcid (overlaps with this tile's gather+compute)
                int pcn = p0 + 4 + (lane & 3);
                if (pcn >= eend) pcn = eend - 1;
                int2 se_n = srcid[pcn];

                uint2 kvr[4]; float4 eav[4];
#pragma unroll
                for (int j = 0; j < 4; ++j) {
                    int sj = __builtin_amdgcn_readlane(se.x, j);
                    int ej = __builtin_amdgcn_readlane(se.y, j);
                    kvr[j] = reinterpret_cast<const uint2*>(kvb)[(size_t)(unsigned)sj * 64 + lane];
                    eav[j] = *reinterpret_cast<const float4*>(
                        edge_attr + (size_t)(unsigned)ej * 32 + sub * 4);
                }

                int cnt = eend - p0; if (cnt > 4) cnt = 4;
#pragma unroll
                for (int j = 0; j < 4; ++j) {
                    float k0 = asf(kvr[j].x & 0xffff0000u);
                    float v0 = asf(kvr[j].x << 16);
                    float k1 = asf(kvr[j].y & 0xffff0000u);
                    float v1 = asf(kvr[j].y << 16);
                    float pr = fmaf(q1, k1, q0 * k0);
                    pr = fmaf(qw0, eav[j].x, pr);
                    pr = fmaf(qw1, eav[j].y, pr);
                    pr = fmaf(qw2, eav[j].z, pr);
                    pr = fmaf(qw3, eav[j].w, pr);
                    pr += __shfl_xor(pr, 1);
                    pr += __shfl_xor(pr, 2);
                    pr += __shfl_xor(pr, 4);   // per-head dot over 8 lanes
                    float w = (j < cnt) ? __builtin_amdgcn_exp2f(pr) : 0.f;
                    lsum += w;
                    a0 = fmaf(w, v0, a0);
                    a1 = fmaf(w, v1, a1);
                    wea0 = fmaf(w, eav[j].x, wea0);
                    wea1 = fmaf(w, eav[j].y, wea1);
                    wea2 = fmaf(w, eav[j].z, wea2);
                    wea3 = fmaf(w, eav[j].w, wea3);
                }
                se = se_n;
            }

            // e-part of PV for THIS lane's channels c0,c0+1:
            //   ep_c = sum_{d=0..31} wea[h,d] * We[d][c]
            // wea distributed over head group by d (lane sub holds 4*sub..4*sub+3):
            // BROADCAST each sub's 4 values (butterfly would mix channels — R8 bug).
            int c0 = 2 * lane;
            float ep0 = 0.f, ep1 = 0.f;
            int gbase = lane & 56;   // first lane of this head group
#pragma unroll
            for (int s = 0; s < 8; ++s) {
                float w0 = __shfl(wea0, gbase + s);
                float w1 = __shfl(wea1, gbase + s);
                float w2 = __shfl(wea2, gbase + s);
                float w3 = __shfl(wea3, gbase + s);
                const float* r0 = &wes[4 * s + 0][0];
                const float* r1 = &wes[4 * s + 1][0];
                const float* r2 = &wes[4 * s + 2][0];
                const float* r3 = &wes[4 * s + 3][0];
                ep0 = fmaf(w0, r0[c0], ep0); ep0 = fmaf(w1, r1[c0], ep0);
                ep0 = fmaf(w2, r2[c0], ep0); ep0 = fmaf(w3, r3[c0], ep0);
                ep1 = fmaf(w0, r0[c0 + 1], ep1); ep1 = fmaf(w1, r1[c0 + 1], ep1);
                ep1 = fmaf(w2, r2[c0 + 1], ep1); ep1 = fmaf(w3, r3[c0 + 1], ep1);
            }

            float rden = 1.f / (lsum + 1e-16f);
            float attn0 = (a0 + ep0) * rden;
            float attn1 = (a1 + ep1) * rden;
            unsigned int skp = reinterpret_cast<const unsigned int*>(skipb)[(size_t)n * 64 + lane];
            float pre0 = attn0 + asf(skp << 16);          // skipb = skip + x
            float pre1 = attn1 + asf(skp & 0xffff0000u);
            float s1 = pre0 + pre1, s2 = pre0 * pre0 + pre1 * pre1;
#pragma unroll
            for (int off = 1; off < 64; off <<= 1) {
                s1 += __shfl_xor(s1, off);
                s2 += __shfl_xor(s2, off);
            }
            float mu = s1 * (1.f / 128.f);
            float var = s2 * (1.f / 128.f) - mu * mu;
            float inv = rsqrtf(var + 1e-5f);
            float2 g  = *reinterpret_cast<const float2*>(ln1g + c0);
            float2 bb = *reinterpret_cast<const float2*>(ln1b + c0);
            float h0 = (pre0 - mu) * inv * g.x + bb.x;
            float h1 = (pre1 - mu) * inv * g.y + bb.y;
            unsigned int hu = (unsigned int)(unsigned short)f2bs(h0) |
                              ((unsigned int)(unsigned short)f2bs(h1) << 16);
            reinterpret_cast<unsigned int*>(hb)[(size_t)n * 64 + lane] = hu;
        }
    }
}

// ---------------- FFN via MFMA + LN2 ----------------
__global__ __launch_bounds__(256) void k_ffn(
    const bf16* __restrict__ hb,
    const bf16* __restrict__ w1p, const float* __restrict__ b1,
    const bf16* __restrict__ w2p, const float* __restrict__ b2,
    const float* __restrict__ ln2g, const float* __restrict__ ln2b,
    float* __restrict__ out)
{
    __shared__ __align__(16) short hs[32][136];
    __shared__ __align__(16) short t1s[32][520];
    float* fs = reinterpret_cast<float*>(&t1s[0][0]);  // [32][132] after t1s is dead
    const int t = threadIdx.x;
    const int wave = t >> 6, lane = t & 63;
    const int quad = lane >> 4, m = lane & 15;
    const int n0 = blockIdx.x * 32;

    for (int idx = t; idx < 32 * 16; idx += 256) {
        int row = idx >> 4, g = idx & 15;
        int node = n0 + row;
        if (node < NN) {
            *reinterpret_cast<float4*>(&hs[row][g * 8]) =
                *reinterpret_cast<const float4*>(&hb[(size_t)node * 128 + g * 8]);
        } else {
            float4 z = {0.f, 0.f, 0.f, 0.f};
            *reinterpret_cast<float4*>(&hs[row][g * 8]) = z;
        }
    }
    __syncthreads();

    floatx4 acc1[2][8];
#pragma unroll
    for (int mt = 0; mt < 2; ++mt)
#pragma unroll
        for (int nt = 0; nt < 8; ++nt) acc1[mt][nt] = (floatx4){0.f, 0.f, 0.f, 0.f};
#pragma unroll
    for (int kstep = 0; kstep < 4; ++kstep) {
        short8 af0 = *reinterpret_cast<const short8*>(&hs[m][kstep * 32 + quad * 8]);
        short8 af1 = *reinterpret_cast<const short8*>(&hs[16 + m][kstep * 32 + quad * 8]);
#pragma unroll
        for (int nt = 0; nt < 8; ++nt) {
            short8 bf = *reinterpret_cast<const short8*>(
                reinterpret_cast<const short*>(w1p) + (((wave * 8 + nt) * 4 + kstep) * 64 + lane) * 8);
            acc1[0][nt] = __builtin_amdgcn_mfma_f32_16x16x32_bf16(af0, bf, acc1[0][nt], 0, 0, 0);
            acc1[1][nt] = __builtin_amdgcn_mfma_f32_16x16x32_bf16(af1, bf, acc1[1][nt], 0, 0, 0);
        }
    }
#pragma unroll
    for (int nt = 0; nt < 8; ++nt) {
        float bs = b1[wave * 128 + nt * 16 + m];
#pragma unroll
        for (int mt = 0; mt < 2; ++mt)
#pragma unroll
            for (int r = 0; r < 4; ++r)
                t1s[mt * 16 + quad * 4 + r][wave * 128 + nt * 16 + m] =
                    f2bs(fmaxf(acc1[mt][nt][r] + bs, 0.f));
    }
    __syncthreads();

    floatx4 acc2[2][2];
#pragma unroll
    for (int mt = 0; mt < 2; ++mt)
#pragma unroll
        for (int nt = 0; nt < 2; ++nt) acc2[mt][nt] = (floatx4){0.f, 0.f, 0.f, 0.f};
#pragma unroll
    for (int kstep = 0; kstep < 16; ++kstep) {
        short8 af0 = *reinterpret_cast<const short8*>(&t1s[m][kstep * 32 + quad * 8]);
        short8 af1 = *reinterpret_cast<const short8*>(&t1s[16 + m][kstep * 32 + quad * 8]);
#pragma unroll
        for (int nt = 0; nt < 2; ++nt) {
            short8 bf = *reinterpret_cast<const short8*>(
                reinterpret_cast<const short*>(w2p) + (((wave * 2 + nt) * 16 + kstep) * 64 + lane) * 8);
            acc2[0][nt] = __builtin_amdgcn_mfma_f32_16x16x32_bf16(af0, bf, acc2[0][nt], 0, 0, 0);
            acc2[1][nt] = __builtin_amdgcn_mfma_f32_16x16x32_bf16(af1, bf, acc2[1][nt], 0, 0, 0);
        }
    }
    __syncthreads();
#pragma unroll
    for (int nt = 0; nt < 2; ++nt) {
        int col = (wave * 2 + nt) * 16 + m;
        float bs = b2[col];
#pragma unroll
        for (int mt = 0; mt < 2; ++mt)
#pragma unroll
            for (int r = 0; r < 4; ++r)
                fs[(mt * 16 + quad * 4 + r) * 132 + col] = acc2[mt][nt][r] + bs;
    }
    __syncthreads();

    for (int rr = 0; rr < 8; ++rr) {
        int row = wave * 8 + rr;
        int node = n0 + row;
        float p0 = bs2f(hs[row][lane]) + fs[row * 132 + lane];
        float p1 = bs2f(hs[row][lane + 64]) + fs[row * 132 + lane + 64];
        float s1 = p0 + p1, s2 = p0 * p0 + p1 * p1;
#pragma unroll
        for (int off = 1; off < 64; off <<= 1) {
            s1 += __shfl_xor(s1, off);
            s2 += __shfl_xor(s2, off);
        }
        float mu = s1 * (1.f / 128.f);
        float var = s2 * (1.f / 128.f) - mu * mu;
        float inv = rsqrtf(var + 1e-5f);
        if (node < NN) {
            out[(size_t)node * 128 + lane] = (p0 - mu) * inv * ln2g[lane] + ln2b[lane];
            out[(size_t)node * 128 + lane + 64] = (p1 - mu) * inv * ln2g[lane + 64] + ln2b[lane + 64];
        }
    }
}

extern "C" void kernel_launch(void* const* d_in, const int* in_sizes, int n_in,
                              void* d_out, int out_size, void* d_ws, size_t ws_size,
                              hipStream_t stream)
{
    const float* x    = (const float*)d_in[0];
    const int*   ei   = (const int*)d_in[1];
    const float* ea   = (const float*)d_in[2];
    const float* Wq   = (const float*)d_in[3];
    const float* bq   = (const float*)d_in[4];
    const float* Wk   = (const float*)d_in[5];
    const float* bk   = (const float*)d_in[6];
    const float* Wv   = (const float*)d_in[7];
    const float* bv   = (const float*)d_in[8];
    const float* We   = (const float*)d_in[9];
    const float* Wsk  = (const float*)d_in[10];
    const float* bsk  = (const float*)d_in[11];
    const float* ln1g = (const float*)d_in[12];
    const float* ln1b = (const float*)d_in[13];
    const float* W1   = (const float*)d_in[14];
    const float* b1   = (const float*)d_in[15];
    const float* W2   = (const float*)d_in[16];
    const float* b2   = (const float*)d_in[17];
    const float* ln2g = (const float*)d_in[18];
    const float* ln2b = (const float*)d_in[19];

    char* ws = (char*)d_ws;
    size_t off = 0;
    auto alloc = [&](size_t bytes) -> void* {
        void* p = ws + off;
        off += (bytes + 255) & ~(size_t)255;
        return p;
    };
    int*   flag     = (int*)alloc(256);
    int*   qcounter = (int*)alloc((size_t)NQC * 16 * 4);
    int*   deg      = (int*)alloc((size_t)NN * 4);
    int*   cursor   = (int*)alloc((size_t)NN * 4);
    int*   rowstart = (int*)alloc((size_t)(NN + 1) * 4);
    int2*  srcid    = (int2*)alloc((size_t)EE * 8);
    bf16*  qb       = (bf16*)alloc((size_t)NN * 128 * 2);
    unsigned int* kvb = (unsigned int*)alloc((size_t)NN * 128 * 4);
    bf16*  skipb    = (bf16*)alloc((size_t)NN * 128 * 2);
    bf16*  hb       = (bf16*)alloc((size_t)NN * 128 * 2);
    uint2* qWb      = (uint2*)alloc((size_t)NN * 64 * 8);   // 8 heads x 32 d, bf16
    bf16*  wqp      = (bf16*)alloc((size_t)16384 * 2);
    bf16*  wkp      = (bf16*)alloc((size_t)16384 * 2);
    bf16*  wvp      = (bf16*)alloc((size_t)16384 * 2);
    bf16*  wskp     = (bf16*)alloc((size_t)16384 * 2);
    bf16*  w1p      = (bf16*)alloc((size_t)65536 * 2);
    bf16*  w2p      = (bf16*)alloc((size_t)65536 * 2);
    bf16*  wqwp     = (bf16*)alloc((size_t)32768 * 2);
    float* bqW      = (float*)alloc((size_t)256 * 4);

    k_packall<<<769, 256, 0, stream>>>(
        Wq, Wk, Wv, Wsk, W1, W2, wqp, wkp, wvp, wskp, w1p, w2p,
        ei, flag, deg, cursor, qcounter);
    k_wqw<<<128, 256, 0, stream>>>(Wq, We, bq, wqwp, bqW);
    k_hist<<<(EE / 2 + 255) / 256, 256, 0, stream>>>(ei, flag, deg);
    k_proj<<<(NN + 31) / 32, 256, 0, stream>>>(x, wqp, wkp, wvp, wskp, wqwp, bqW,
                                               bq, bk, bv, bsk, qb, kvb, skipb, qWb);
    k_scan<<<1, 1024, 0, stream>>>(deg, rowstart);
    k_scatter<<<(EE + 255) / 256, 256, 0, stream>>>(ei, flag, rowstart, cursor, srcid);
    k_attn<<<2048, 256, 0, stream>>>(ea, We, qb, qWb, kvb, skipb,
                                     rowstart, srcid, ln1g, ln1b, qcounter, hb);
    k_ffn<<<(NN + 31) / 32, 256, 0, stream>>>(hb, w1p, b1, w2p, b2, ln2g, ln2b, (float*)d_out);
}

// Round 11
// 669.124 us; speedup vs baseline: 1.2592x; 1.2592x over previous
//
#include <hip/hip_runtime.h>
#include <hip/hip_bf16.h>

using bf16 = __hip_bfloat16;
typedef __attribute__((ext_vector_type(8))) short short8;
typedef __attribute__((ext_vector_type(4))) float floatx4;

#define NN 50000
#define EE 800000
#define DD 128
#define HH 8
#define CC 16
#define EDD 32
#define DF 512
#define NQC 64      // partitioned queue counters
#define PART 782    // ceil(NN/NQC)

__device__ __forceinline__ float bs2f(short s) {
    bf16 h = *reinterpret_cast<bf16*>(&s);
    return __bfloat162float(h);
}
__device__ __forceinline__ float bu2f(unsigned short s) {
    unsigned int u = ((unsigned int)s) << 16;
    return *reinterpret_cast<float*>(&u);
}
__device__ __forceinline__ short f2bs(float v) {
    bf16 h = __float2bfloat16(v);
    return *reinterpret_cast<short*>(&h);
}
__device__ __forceinline__ float asf(unsigned int u) {
    return *reinterpret_cast<float*>(&u);
}

__device__ __forceinline__ int clampn(int v)
{
    return (v < 0) ? 0 : (v >= NN ? NN - 1 : v);
}

// ---- pack fp32 weights [K][N] into per-lane MFMA B-frag layout (bf16) ----
// + zero deg/cursor/qcounter; + detect edge_index width (thread 196608)
__global__ void k_packall(const float* __restrict__ Wq, const float* __restrict__ Wk,
                          const float* __restrict__ Wv, const float* __restrict__ Wsk,
                          const float* __restrict__ W1, const float* __restrict__ W2,
                          bf16* __restrict__ wqp, bf16* __restrict__ wkp,
                          bf16* __restrict__ wvp, bf16* __restrict__ wskp,
                          bf16* __restrict__ w1p, bf16* __restrict__ w2p,
                          const int* __restrict__ ei, int* __restrict__ flag,
                          int* __restrict__ deg, int* __restrict__ cursor,
                          int* __restrict__ qcounter)
{
    int idx = blockIdx.x * 256 + threadIdx.x;
    if (idx < NN) deg[idx] = 0;
    else if (idx < 2 * NN) cursor[idx - NN] = 0;
    else if (idx < 2 * NN + NQC * 16) qcounter[idx - 2 * NN] = 0;

    const float* W; bf16* out; int ksteps, N, local;
    if (idx < 65536) {
        int wsel = idx >> 14; local = idx & 16383;
        W   = (wsel == 0) ? Wq  : (wsel == 1) ? Wk  : (wsel == 2) ? Wv  : Wsk;
        out = (wsel == 0) ? wqp : (wsel == 1) ? wkp : (wsel == 2) ? wvp : wskp;
        ksteps = 4; N = 128;
    } else if (idx < 131072) { local = idx - 65536;  W = W1; out = w1p; ksteps = 4;  N = 512; }
    else if (idx < 196608)   { local = idx - 131072; W = W2; out = w2p; ksteps = 16; N = 128; }
    else {
        if (idx == 196608) {
            int all0 = 1;
            for (int i = 0; i < 16; ++i) all0 &= (ei[2 * i + 1] == 0);
            flag[0] = all0;    // 1 => int64 layout, 0 => int32
        }
        return;
    }
    int j = local & 7, lane = (local >> 3) & 63, rest = local >> 9;
    int kstep = rest % ksteps, ntile = rest / ksteps;
    int quad = lane >> 4, m = lane & 15;
    int k = kstep * 32 + quad * 8 + j;
    int n = ntile * 16 + m;
    out[local] = __float2bfloat16(W[(size_t)k * N + n]);
}

// ---- WqW = Wq @ We2 (block-diag fold) -> MFMA B-frags; bqW = bq @ We2 ----
// WqW[r, h*32+d] = sum_c Wq[r, h*16+c] * We[d, h*16+c]
__global__ void k_wqw(const float* __restrict__ Wq, const float* __restrict__ We,
                      const float* __restrict__ bq,
                      bf16* __restrict__ wqwp, float* __restrict__ bqW)
{
    int idx = blockIdx.x * 256 + threadIdx.x;   // 128*256 = 32768
    int k = idx >> 8, n = idx & 255;
    int h = n >> 5, d = n & 31;
    const float* wq = Wq + (size_t)k * 128 + h * 16;
    const float* we = We + (size_t)d * 128 + h * 16;
    float v = 0.f;
#pragma unroll
    for (int c = 0; c < 16; ++c) v = fmaf(wq[c], we[c], v);
    int kstep = k >> 5, quad = (k >> 3) & 3, j = k & 7;
    int nt = n >> 4, m = n & 15;
    wqwp[(((nt * 4) + kstep) * 64 + quad * 16 + m) * 8 + j] = __float2bfloat16(v);
    if (k == 0) {
        const float* bqh = bq + h * 16;
        float bv = 0.f;
#pragma unroll
        for (int c = 0; c < 16; ++c) bv = fmaf(bqh[c], we[c], bv);
        bqW[n] = bv;
    }
}

// -------- projections via MFMA: q, kv packed (k hi | v lo), skip(+x), qW --------
__global__ __launch_bounds__(256) void k_proj(
    const float* __restrict__ x,
    const bf16* __restrict__ wqp, const bf16* __restrict__ wkp,
    const bf16* __restrict__ wvp, const bf16* __restrict__ wskp,
    const bf16* __restrict__ wqwp, const float* __restrict__ bqW,
    const float* __restrict__ bq, const float* __restrict__ bk,
    const float* __restrict__ bv, const float* __restrict__ bsk,
    bf16* __restrict__ qb, unsigned int* __restrict__ kvb,
    bf16* __restrict__ skipb, uint2* __restrict__ qWb)
{
    __shared__ __align__(16) short xs[32][136];
    __shared__ __align__(16) short os[32][520];
    short* osf = &os[0][0];
    const int t = threadIdx.x;
    const int wave = t >> 6, lane = t & 63;
    const int quad = lane >> 4, m = lane & 15;
    const int n0 = blockIdx.x * 32;

    for (int idx = t; idx < 32 * 32; idx += 256) {
        int row = idx >> 5, g = idx & 31;
        int node = n0 + row;
        float4 xv = {0.f, 0.f, 0.f, 0.f};
        if (node < NN) xv = *reinterpret_cast<const float4*>(&x[(size_t)node * 128 + g * 4]);
        short4 s4;
        s4.x = f2bs(xv.x); s4.y = f2bs(xv.y); s4.z = f2bs(xv.z); s4.w = f2bs(xv.w);
        *reinterpret_cast<short4*>(&xs[row][g * 4]) = s4;
    }
    __syncthreads();

    const bf16* Wp = (wave == 0) ? wqp : (wave == 1) ? wkp : (wave == 2) ? wvp : wskp;
    const float* bias = (wave == 0) ? bq : (wave == 1) ? bk : (wave == 2) ? bv : bsk;

    floatx4 acc[2][8];
#pragma unroll
    for (int mt = 0; mt < 2; ++mt)
#pragma unroll
        for (int nt = 0; nt < 8; ++nt) acc[mt][nt] = (floatx4){0.f, 0.f, 0.f, 0.f};

#pragma unroll
    for (int kstep = 0; kstep < 4; ++kstep) {
        short8 af0 = *reinterpret_cast<const short8*>(&xs[m][kstep * 32 + quad * 8]);
        short8 af1 = *reinterpret_cast<const short8*>(&xs[16 + m][kstep * 32 + quad * 8]);
#pragma unroll
        for (int nt = 0; nt < 8; ++nt) {
            short8 bf = *reinterpret_cast<const short8*>(
                reinterpret_cast<const short*>(Wp) + ((nt * 4 + kstep) * 64 + lane) * 8);
            acc[0][nt] = __builtin_amdgcn_mfma_f32_16x16x32_bf16(af0, bf, acc[0][nt], 0, 0, 0);
            acc[1][nt] = __builtin_amdgcn_mfma_f32_16x16x32_bf16(af1, bf, acc[1][nt], 0, 0, 0);
        }
    }
#pragma unroll
    for (int nt = 0; nt < 8; ++nt) {
        float bs = bias[nt * 16 + m];
#pragma unroll
        for (int mt = 0; mt < 2; ++mt)
#pragma unroll
            for (int r = 0; r < 4; ++r)
                os[mt * 16 + quad * 4 + r][wave * 128 + nt * 16 + m] = f2bs(acc[mt][nt][r] + bs);
    }
    __syncthreads();
    // q (u32 lo=even ch), skip+x, kv packed (k in HIGH half, v in LOW half)
    for (int idx = t; idx < 32 * 64; idx += 256) {
        int row = idx >> 6, c = idx & 63;
        int node = n0 + row;
        if (node >= NN) continue;
        unsigned int qu  = *reinterpret_cast<const unsigned int*>(&os[row][2 * c]);
        unsigned int ku  = *reinterpret_cast<const unsigned int*>(&os[row][128 + 2 * c]);
        unsigned int vu  = *reinterpret_cast<const unsigned int*>(&os[row][256 + 2 * c]);
        float sk0 = bs2f(os[row][384 + 2 * c])     + bs2f(xs[row][2 * c]);
        float sk1 = bs2f(os[row][384 + 2 * c + 1]) + bs2f(xs[row][2 * c + 1]);
        unsigned int sku = (unsigned int)(unsigned short)f2bs(sk0) |
                           ((unsigned int)(unsigned short)f2bs(sk1) << 16);
        reinterpret_cast<unsigned int*>(qb)[(size_t)node * 64 + c] = qu;
        reinterpret_cast<unsigned int*>(skipb)[(size_t)node * 64 + c] = sku;
        uint2 kv;
        kv.x = (vu & 0xffffu) | (ku << 16);          // ch 2c  : k hi, v lo
        kv.y = (vu >> 16) | (ku & 0xffff0000u);      // ch 2c+1: k hi, v lo
        reinterpret_cast<uint2*>(kvb)[(size_t)node * 64 + c] = kv;
    }
    __syncthreads();   // all consumers of os done

    // ---- pass 2: qW = x @ WqW + bqW (256 cols, 4 ntiles per wave) ----
    floatx4 acc2[2][4];
#pragma unroll
    for (int mt = 0; mt < 2; ++mt)
#pragma unroll
        for (int nt = 0; nt < 4; ++nt) acc2[mt][nt] = (floatx4){0.f, 0.f, 0.f, 0.f};
#pragma unroll
    for (int kstep = 0; kstep < 4; ++kstep) {
        short8 af0 = *reinterpret_cast<const short8*>(&xs[m][kstep * 32 + quad * 8]);
        short8 af1 = *reinterpret_cast<const short8*>(&xs[16 + m][kstep * 32 + quad * 8]);
#pragma unroll
        for (int nt = 0; nt < 4; ++nt) {
            short8 bf = *reinterpret_cast<const short8*>(
                reinterpret_cast<const short*>(wqwp) + (((wave * 4 + nt) * 4 + kstep) * 64 + lane) * 8);
            acc2[0][nt] = __builtin_amdgcn_mfma_f32_16x16x32_bf16(af0, bf, acc2[0][nt], 0, 0, 0);
            acc2[1][nt] = __builtin_amdgcn_mfma_f32_16x16x32_bf16(af1, bf, acc2[1][nt], 0, 0, 0);
        }
    }
#pragma unroll
    for (int nt = 0; nt < 4; ++nt) {
        int col = wave * 64 + nt * 16 + m;
        float bs = bqW[col];
#pragma unroll
        for (int mt = 0; mt < 2; ++mt)
#pragma unroll
            for (int r = 0; r < 4; ++r)
                osf[(mt * 16 + quad * 4 + r) * 256 + col] = f2bs(acc2[mt][nt][r] + bs);
    }
    __syncthreads();
    for (int idx = t; idx < 32 * 64; idx += 256) {
        int row = idx >> 6, c2 = idx & 63;
        int node = n0 + row;
        if (node >= NN) continue;
        qWb[(size_t)node * 64 + c2] = *reinterpret_cast<const uint2*>(&osf[row * 256 + c2 * 4]);
    }
}

// ---------------- CSR build ----------------
__global__ void k_hist(const int* __restrict__ ei, const int* __restrict__ flag,
                       int* __restrict__ deg)
{
    int tt = blockIdx.x * 256 + threadIdx.x;
    int i0 = tt * 2;
    if (i0 >= EE) return;
    int d0, d1;
    if (flag[0]) {
        int4 v = *reinterpret_cast<const int4*>(&ei[2 * EE + 2 * i0]);
        d0 = v.x; d1 = v.z;
    } else {
        int2 v = *reinterpret_cast<const int2*>(&ei[EE + i0]);
        d0 = v.x; d1 = v.y;
    }
    atomicAdd(&deg[clampn(d0)], 1);
    atomicAdd(&deg[clampn(d1)], 1);
}

__global__ __launch_bounds__(1024) void k_scan(const int* __restrict__ deg,
                                               int* __restrict__ rowstart)
{
    __shared__ int s[1024];
    const int t = threadIdx.x;
    const int CH = 49;
    int base = t * CH;
    int sum = 0;
    for (int i = 0; i < CH; i++) {
        int idx = base + i;
        if (idx < NN) sum += deg[idx];
    }
    s[t] = sum;
    __syncthreads();
    int own = sum;
    for (int off = 1; off < 1024; off <<= 1) {
        int v = (t >= off) ? s[t - off] : 0;
        __syncthreads();
        s[t] += v;
        __syncthreads();
    }
    int run = s[t] - own;
    for (int i = 0; i < CH; i++) {
        int idx = base + i;
        if (idx < NN) {
            rowstart[idx] = run;
            run += deg[idx];
        }
    }
    if (t == 0) rowstart[NN] = EE;
}

// scatter: permutation only — one scattered 8B store {src, eid} per edge
__global__ void k_scatter(const int* __restrict__ ei, const int* __restrict__ flag,
                          const int* __restrict__ rowstart,
                          int* __restrict__ cursor, int2* __restrict__ srcid)
{
    int i = blockIdx.x * 256 + threadIdx.x;
    if (i >= EE) return;
    int is64 = flag[0];
    int d = clampn(is64 ? ei[2 * EE + 2 * i] : ei[EE + i]);
    int s = clampn(is64 ? ei[2 * i] : ei[i]);
    int pos = rowstart[d] + atomicAdd(&cursor[d], 1);
    srcid[pos] = make_int2(s, i);
}

// -------- fused attention: NO MFMA — factored-e algebra, register-lean --------
// alpha = q.k + ea.qW[dst];  PV e-part via wea accumulator resolved against We.
// 2-edge batches (kvr+eav = 12 buffer VGPRs), no prefetch double-buffer;
// launch_bounds(256,4) caps at 128 (no spill possible), target natural <=64.
__global__ __launch_bounds__(256, 4) void k_attn(
    const float* __restrict__ edge_attr, const float* __restrict__ We,
    const bf16* __restrict__ qb, const uint2* __restrict__ qWb,
    const unsigned int* __restrict__ kvb, const bf16* __restrict__ skipb,
    const int* __restrict__ rowstart, const int2* __restrict__ srcid,
    const float* __restrict__ ln1g, const float* __restrict__ ln1b,
    int* __restrict__ qcounter, bf16* __restrict__ hb)
{
    __shared__ float wes[32][128];   // We staged fp32 (16KB)
    const int t = threadIdx.x;
    const int wave = t >> 6, lane = t & 63;
    const int sub = lane & 7;

    for (int idx = t; idx < 1024; idx += 256)
        reinterpret_cast<float4*>(&wes[0][0])[idx] =
            reinterpret_cast<const float4*>(We)[idx];
    __syncthreads();   // only barrier in the kernel

    const float QS = 0.3606737602f;   // 0.25 * log2(e)
    const int gw = blockIdx.x * 4 + wave;
    const int c  = gw & (NQC - 1);
    const int base = c * PART;
    const int cnt_c = (NN - base < PART) ? (NN - base) : PART;
    int* qc = qcounter + c * 16;
    const uint2* kvbl = reinterpret_cast<const uint2*>(kvb) + lane;
    const float4* eap = reinterpret_cast<const float4*>(edge_attr) + sub;

    for (;;) {
        int nl;
        if (lane == 0) nl = atomicAdd(qc, 2);
        nl = __builtin_amdgcn_readfirstlane(nl);
        if (nl >= cnt_c) break;
        const int nhi = (nl + 2 < cnt_c) ? nl + 2 : cnt_c;

        for (int ni = nl; ni < nhi; ++ni) {
            const int n = base + ni;

            unsigned int qp = reinterpret_cast<const unsigned int*>(qb)[(size_t)n * 64 + lane];
            float q0 = asf(qp << 16) * QS;
            float q1 = asf(qp & 0xffff0000u) * QS;
            uint2 qwu = qWb[(size_t)n * 64 + lane];
            float qw0 = asf(qwu.x << 16) * QS;
            float qw1 = asf(qwu.x & 0xffff0000u) * QS;
            float qw2 = asf(qwu.y << 16) * QS;
            float qw3 = asf(qwu.y & 0xffff0000u) * QS;

            const int eoff = rowstart[n], eend = rowstart[n + 1];
            float lsum = 0.f, a0 = 0.f, a1 = 0.f;
            float wea0 = 0.f, wea1 = 0.f, wea2 = 0.f, wea3 = 0.f;

            for (int p0 = eoff; p0 < eend; p0 += 2) {
                int pc = p0 + (lane & 1);
                if (pc >= eend) pc = eend - 1;
                int2 se = srcid[pc];   // lanes alternate the 2 edges; readlane below

                int sj0 = __builtin_amdgcn_readlane(se.x, 0);
                int ej0 = __builtin_amdgcn_readlane(se.y, 0);
                int sj1 = __builtin_amdgcn_readlane(se.x, 1);
                int ej1 = __builtin_amdgcn_readlane(se.y, 1);
                uint2 kvr0 = kvbl[(size_t)(unsigned)sj0 * 64];
                float4 eav0 = eap[(size_t)(unsigned)ej0 * 8];
                uint2 kvr1 = kvbl[(size_t)(unsigned)sj1 * 64];
                float4 eav1 = eap[(size_t)(unsigned)ej1 * 8];

                // edge 0 (always valid: p0 < eend)
                {
                    float k0 = asf(kvr0.x & 0xffff0000u);
                    float v0 = asf(kvr0.x << 16);
                    float k1 = asf(kvr0.y & 0xffff0000u);
                    float v1 = asf(kvr0.y << 16);
                    float pr = fmaf(q1, k1, q0 * k0);
                    pr = fmaf(qw0, eav0.x, pr);
                    pr = fmaf(qw1, eav0.y, pr);
                    pr = fmaf(qw2, eav0.z, pr);
                    pr = fmaf(qw3, eav0.w, pr);
                    pr += __shfl_xor(pr, 1);
                    pr += __shfl_xor(pr, 2);
                    pr += __shfl_xor(pr, 4);   // per-head dot over 8 lanes
                    float w = __builtin_amdgcn_exp2f(pr);
                    lsum += w;
                    a0 = fmaf(w, v0, a0);
                    a1 = fmaf(w, v1, a1);
                    wea0 = fmaf(w, eav0.x, wea0);
                    wea1 = fmaf(w, eav0.y, wea1);
                    wea2 = fmaf(w, eav0.z, wea2);
                    wea3 = fmaf(w, eav0.w, wea3);
                }
                // edge 1 (valid iff p0+1 < eend)
                {
                    float k0 = asf(kvr1.x & 0xffff0000u);
                    float v0 = asf(kvr1.x << 16);
                    float k1 = asf(kvr1.y & 0xffff0000u);
                    float v1 = asf(kvr1.y << 16);
                    float pr = fmaf(q1, k1, q0 * k0);
                    pr = fmaf(qw0, eav1.x, pr);
                    pr = fmaf(qw1, eav1.y, pr);
                    pr = fmaf(qw2, eav1.z, pr);
                    pr = fmaf(qw3, eav1.w, pr);
                    pr += __shfl_xor(pr, 1);
                    pr += __shfl_xor(pr, 2);
                    pr += __shfl_xor(pr, 4);
                    float w = (p0 + 1 < eend) ? __builtin_amdgcn_exp2f(pr) : 0.f;
                    lsum += w;
                    a0 = fmaf(w, v0, a0);
                    a1 = fmaf(w, v1, a1);
                    wea0 = fmaf(w, eav1.x, wea0);
                    wea1 = fmaf(w, eav1.y, wea1);
                    wea2 = fmaf(w, eav1.z, wea2);
                    wea3 = fmaf(w, eav1.w, wea3);
                }
            }

            // e-part of PV for THIS lane's channels c0,c0+1:
            //   ep_c = sum_{d=0..31} wea[h,d] * We[d][c]
            // wea distributed over head group by d (lane sub holds 4*sub..4*sub+3):
            // BROADCAST each sub's 4 values (butterfly would mix channels — R8 bug).
            int c0 = 2 * lane;
            float ep0 = 0.f, ep1 = 0.f;
            int gbase = lane & 56;   // first lane of this head group
#pragma unroll
            for (int s = 0; s < 8; ++s) {
                float w0 = __shfl(wea0, gbase + s);
                float w1 = __shfl(wea1, gbase + s);
                float w2 = __shfl(wea2, gbase + s);
                float w3 = __shfl(wea3, gbase + s);
                const float* r0 = &wes[4 * s + 0][0];
                const float* r1 = &wes[4 * s + 1][0];
                const float* r2 = &wes[4 * s + 2][0];
                const float* r3 = &wes[4 * s + 3][0];
                ep0 = fmaf(w0, r0[c0], ep0); ep0 = fmaf(w1, r1[c0], ep0);
                ep0 = fmaf(w2, r2[c0], ep0); ep0 = fmaf(w3, r3[c0], ep0);
                ep1 = fmaf(w0, r0[c0 + 1], ep1); ep1 = fmaf(w1, r1[c0 + 1], ep1);
                ep1 = fmaf(w2, r2[c0 + 1], ep1); ep1 = fmaf(w3, r3[c0 + 1], ep1);
            }

            float rden = 1.f / (lsum + 1e-16f);
            float attn0 = (a0 + ep0) * rden;
            float attn1 = (a1 + ep1) * rden;
            unsigned int skp = reinterpret_cast<const unsigned int*>(skipb)[(size_t)n * 64 + lane];
            float pre0 = attn0 + asf(skp << 16);          // skipb = skip + x
            float pre1 = attn1 + asf(skp & 0xffff0000u);
            float s1 = pre0 + pre1, s2 = pre0 * pre0 + pre1 * pre1;
#pragma unroll
            for (int off = 1; off < 64; off <<= 1) {
                s1 += __shfl_xor(s1, off);
                s2 += __shfl_xor(s2, off);
            }
            float mu = s1 * (1.f / 128.f);
            float var = s2 * (1.f / 128.f) - mu * mu;
            float inv = rsqrtf(var + 1e-5f);
            float2 g  = *reinterpret_cast<const float2*>(ln1g + c0);
            float2 bb = *reinterpret_cast<const float2*>(ln1b + c0);
            float h0 = (pre0 - mu) * inv * g.x + bb.x;
            float h1 = (pre1 - mu) * inv * g.y + bb.y;
            unsigned int hu = (unsigned int)(unsigned short)f2bs(h0) |
                              ((unsigned int)(unsigned short)f2bs(h1) << 16);
            reinterpret_cast<unsigned int*>(hb)[(size_t)n * 64 + lane] = hu;
        }
    }
}

// ---------------- FFN via MFMA + LN2 ----------------
__global__ __launch_bounds__(256) void k_ffn(
    const bf16* __restrict__ hb,
    const bf16* __restrict__ w1p, const float* __restrict__ b1,
    const bf16* __restrict__ w2p, const float* __restrict__ b2,
    const float* __restrict__ ln2g, const float* __restrict__ ln2b,
    float* __restrict__ out)
{
    __shared__ __align__(16) short hs[32][136];
    __shared__ __align__(16) short t1s[32][520];
    float* fs = reinterpret_cast<float*>(&t1s[0][0]);  // [32][132] after t1s is dead
    const int t = threadIdx.x;
    const int wave = t >> 6, lane = t & 63;
    const int quad = lane >> 4, m = lane & 15;
    const int n0 = blockIdx.x * 32;

    for (int idx = t; idx < 32 * 16; idx += 256) {
        int row = idx >> 4, g = idx & 15;
        int node = n0 + row;
        if (node < NN) {
            *reinterpret_cast<float4*>(&hs[row][g * 8]) =
                *reinterpret_cast<const float4*>(&hb[(size_t)node * 128 + g * 8]);
        } else {
            float4 z = {0.f, 0.f, 0.f, 0.f};
            *reinterpret_cast<float4*>(&hs[row][g * 8]) = z;
        }
    }
    __syncthreads();

    floatx4 acc1[2][8];
#pragma unroll
    for (int mt = 0; mt < 2; ++mt)
#pragma unroll
        for (int nt = 0; nt < 8; ++nt) acc1[mt][nt] = (floatx4){0.f, 0.f, 0.f, 0.f};
#pragma unroll
    for (int kstep = 0; kstep < 4; ++kstep) {
        short8 af0 = *reinterpret_cast<const short8*>(&hs[m][kstep * 32 + quad * 8]);
        short8 af1 = *reinterpret_cast<const short8*>(&hs[16 + m][kstep * 32 + quad * 8]);
#pragma unroll
        for (int nt = 0; nt < 8; ++nt) {
            short8 bf = *reinterpret_cast<const short8*>(
                reinterpret_cast<const short*>(w1p) + (((wave * 8 + nt) * 4 + kstep) * 64 + lane) * 8);
            acc1[0][nt] = __builtin_amdgcn_mfma_f32_16x16x32_bf16(af0, bf, acc1[0][nt], 0, 0, 0);
            acc1[1][nt] = __builtin_amdgcn_mfma_f32_16x16x32_bf16(af1, bf, acc1[1][nt], 0, 0, 0);
        }
    }
#pragma unroll
    for (int nt = 0; nt < 8; ++nt) {
        float bs = b1[wave * 128 + nt * 16 + m];
#pragma unroll
        for (int mt = 0; mt < 2; ++mt)
#pragma unroll
            for (int r = 0; r < 4; ++r)
                t1s[mt * 16 + quad * 4 + r][wave * 128 + nt * 16 + m] =
                    f2bs(fmaxf(acc1[mt][nt][r] + bs, 0.f));
    }
    __syncthreads();

    floatx4 acc2[2][2];
#pragma unroll
    for (int mt = 0; mt < 2; ++mt)
#pragma unroll
        for (int nt = 0; nt < 2; ++nt) acc2[mt][nt] = (floatx4){0.f, 0.f, 0.f, 0.f};
#pragma unroll
    for (int kstep = 0; kstep < 16; ++kstep) {
        short8 af0 = *reinterpret_cast<const short8*>(&t1s[m][kstep * 32 + quad * 8]);
        short8 af1 = *reinterpret_cast<const short8*>(&t1s[16 + m][kstep * 32 + quad * 8]);
#pragma unroll
        for (int nt = 0; nt < 2; ++nt) {
            short8 bf = *reinterpret_cast<const short8*>(
                reinterpret_cast<const short*>(w2p) + (((wave * 2 + nt) * 16 + kstep) * 64 + lane) * 8);
            acc2[0][nt] = __builtin_amdgcn_mfma_f32_16x16x32_bf16(af0, bf, acc2[0][nt], 0, 0, 0);
            acc2[1][nt] = __builtin_amdgcn_mfma_f32_16x16x32_bf16(af1, bf, acc2[1][nt], 0, 0, 0);
        }
    }
    __syncthreads();
#pragma unroll
    for (int nt = 0; nt < 2; ++nt) {
        int col = (wave * 2 + nt) * 16 + m;
        float bs = b2[col];
#pragma unroll
        for (int mt = 0; mt < 2; ++mt)
#pragma unroll
            for (int r = 0; r < 4; ++r)
                fs[(mt * 16 + quad * 4 + r) * 132 + col] = acc2[mt][nt][r] + bs;
    }
    __syncthreads();

    for (int rr = 0; rr < 8; ++rr) {
        int row = wave * 8 + rr;
        int node = n0 + row;
        float p0 = bs2f(hs[row][lane]) + fs[row * 132 + lane];
        float p1 = bs2f(hs[row][lane + 64]) + fs[row * 132 + lane + 64];
        float s1 = p0 + p1, s2 = p0 * p0 + p1 * p1;
#pragma unroll
        for (int off = 1; off < 64; off <<= 1) {
            s1 += __shfl_xor(s1, off);
            s2 += __shfl_xor(s2, off);
        }
        float mu = s1 * (1.f / 128.f);
        float var = s2 * (1.f / 128.f) - mu * mu;
        float inv = rsqrtf(var + 1e-5f);
        if (node < NN) {
            out[(size_t)node * 128 + lane] = (p0 - mu) * inv * ln2g[lane] + ln2b[lane];
            out[(size_t)node * 128 + lane + 64] = (p1 - mu) * inv * ln2g[lane + 64] + ln2b[lane + 64];
        }
    }
}

extern "C" void kernel_launch(void* const* d_in, const int* in_sizes, int n_in,
                              void* d_out, int out_size, void* d_ws, size_t ws_size,
                              hipStream_t stream)
{
    const float* x    = (const float*)d_in[0];
    const int*   ei   = (const int*)d_in[1];
    const float* ea   = (const float*)d_in[2];
    const float* Wq   = (const float*)d_in[3];
    const float* bq   = (const float*)d_in[4];
    const float* Wk   = (const float*)d_in[5];
    const float* bk   = (const float*)d_in[6];
    const float* Wv   = (const float*)d_in[7];
    const float* bv   = (const float*)d_in[8];
    const float* We   = (const float*)d_in[9];
    const float* Wsk  = (const float*)d_in[10];
    const float* bsk  = (const float*)d_in[11];
    const float* ln1g = (const float*)d_in[12];
    const float* ln1b = (const float*)d_in[13];
    const float* W1   = (const float*)d_in[14];
    const float* b1   = (const float*)d_in[15];
    const float* W2   = (const float*)d_in[16];
    const float* b2   = (const float*)d_in[17];
    const float* ln2g = (const float*)d_in[18];
    const float* ln2b = (const float*)d_in[19];

    char* ws = (char*)d_ws;
    size_t off = 0;
    auto alloc = [&](size_t bytes) -> void* {
        void* p = ws + off;
        off += (bytes + 255) & ~(size_t)255;
        return p;
    };
    int*   flag     = (int*)alloc(256);
    int*   qcounter = (int*)alloc((size_t)NQC * 16 * 4);
    int*   deg      = (int*)alloc((size_t)NN * 4);
    int*   cursor   = (int*)alloc((size_t)NN * 4);
    int*   rowstart = (int*)alloc((size_t)(NN + 1) * 4);
    int2*  srcid    = (int2*)alloc((size_t)EE * 8);
    bf16*  qb       = (bf16*)alloc((size_t)NN * 128 * 2);
    unsigned int* kvb = (unsigned int*)alloc((size_t)NN * 128 * 4);
    bf16*  skipb    = (bf16*)alloc((size_t)NN * 128 * 2);
    bf16*  hb       = (bf16*)alloc((size_t)NN * 128 * 2);
    uint2* qWb      = (uint2*)alloc((size_t)NN * 64 * 8);   // 8 heads x 32 d, bf16
    bf16*  wqp      = (bf16*)alloc((size_t)16384 * 2);
    bf16*  wkp      = (bf16*)alloc((size_t)16384 * 2);
    bf16*  wvp      = (bf16*)alloc((size_t)16384 * 2);
    bf16*  wskp     = (bf16*)alloc((size_t)16384 * 2);
    bf16*  w1p      = (bf16*)alloc((size_t)65536 * 2);
    bf16*  w2p      = (bf16*)alloc((size_t)65536 * 2);
    bf16*  wqwp     = (bf16*)alloc((size_t)32768 * 2);
    float* bqW      = (float*)alloc((size_t)256 * 4);

    k_packall<<<769, 256, 0, stream>>>(
        Wq, Wk, Wv, Wsk, W1, W2, wqp, wkp, wvp, wskp, w1p, w2p,
        ei, flag, deg, cursor, qcounter);
    k_wqw<<<128, 256, 0, stream>>>(Wq, We, bq, wqwp, bqW);
    k_hist<<<(EE / 2 + 255) / 256, 256, 0, stream>>>(ei, flag, deg);
    k_proj<<<(NN + 31) / 32, 256, 0, stream>>>(x, wqp, wkp, wvp, wskp, wqwp, bqW,
                                               bq, bk, bv, bsk, qb, kvb, skipb, qWb);
    k_scan<<<1, 1024, 0, stream>>>(deg, rowstart);
    k_scatter<<<(EE + 255) / 256, 256, 0, stream>>>(ei, flag, rowstart, cursor, srcid);
    k_attn<<<2048, 256, 0, stream>>>(ea, We, qb, qWb, kvb, skipb,
                                     rowstart, srcid, ln1g, ln1b, qcounter, hb);
    k_ffn<<<(NN + 31) / 32, 256, 0, stream>>>(hb, w1p, b1, w2p, b2, ln2g, ln2b, (float*)d_out);
}

// Round 12
// 520.729 us; speedup vs baseline: 1.6180x; 1.2850x over previous
//
#include <hip/hip_runtime.h>
#include <hip/hip_bf16.h>

using bf16 = __hip_bfloat16;
typedef __attribute__((ext_vector_type(8))) short short8;
typedef __attribute__((ext_vector_type(4))) float floatx4;

#define NN 50000
#define EE 800000
#define DD 128
#define HH 8
#define CC 16
#define EDD 32
#define DF 512
#define NQC 64      // partitioned queue counters
#define PART 782    // ceil(NN/NQC)

__device__ __forceinline__ float b2f(bf16 v) { return __bfloat162float(v); }
__device__ __forceinline__ float bs2f(short s) {
    bf16 h = *reinterpret_cast<bf16*>(&s);
    return __bfloat162float(h);
}
__device__ __forceinline__ float bu2f(unsigned short s) {
    unsigned int u = ((unsigned int)s) << 16;
    return *reinterpret_cast<float*>(&u);
}
__device__ __forceinline__ short f2bs(float v) {
    bf16 h = __float2bfloat16(v);
    return *reinterpret_cast<short*>(&h);
}

__device__ __forceinline__ int clampn(int v)
{
    return (v < 0) ? 0 : (v >= NN ? NN - 1 : v);
}

// ---- pack ALL fp32 weights [K][N] into per-lane MFMA B-frag layout (bf16) ----
// + zero deg/qcounter (replaces hipMemsets)
// + block 784 thread 0: edge_index width detection (int64 has zero high-words)
__global__ void k_packall(const float* __restrict__ Wq, const float* __restrict__ Wk,
                          const float* __restrict__ Wv, const float* __restrict__ Wsk,
                          const float* __restrict__ W1, const float* __restrict__ W2,
                          const float* __restrict__ We,
                          bf16* __restrict__ wqp, bf16* __restrict__ wkp,
                          bf16* __restrict__ wvp, bf16* __restrict__ wskp,
                          bf16* __restrict__ w1p, bf16* __restrict__ w2p,
                          bf16* __restrict__ wep,
                          const int* __restrict__ ei, int* __restrict__ flag,
                          int* __restrict__ deg, int* __restrict__ qcounter)
{
    int idx = blockIdx.x * 256 + threadIdx.x;
    // fused zeroing: deg[0..NN), qcounter[0..NQC*16)
    if (idx < NN) deg[idx] = 0;
    else if (idx < NN + NQC * 16) qcounter[idx - NN] = 0;

    const float* W; bf16* out; int ksteps, N, local;
    if (idx < 65536) {
        int wsel = idx >> 14; local = idx & 16383;
        W   = (wsel == 0) ? Wq  : (wsel == 1) ? Wk  : (wsel == 2) ? Wv  : Wsk;
        out = (wsel == 0) ? wqp : (wsel == 1) ? wkp : (wsel == 2) ? wvp : wskp;
        ksteps = 4; N = 128;
    } else if (idx < 131072) { local = idx - 65536;  W = W1; out = w1p; ksteps = 4;  N = 512; }
    else if (idx < 196608)   { local = idx - 131072; W = W2; out = w2p; ksteps = 16; N = 128; }
    else if (idx < 200704)   { local = idx - 196608; W = We; out = wep; ksteps = 1;  N = 128; }
    else {
        if (idx == 200704) {   // block 784, thread 0: detect
            int all0 = 1;
            for (int i = 0; i < 16; ++i) all0 &= (ei[2 * i + 1] == 0);
            flag[0] = all0;    // 1 => int64 layout, 0 => int32
        }
        return;
    }
    int j = local & 7, lane = (local >> 3) & 63, rest = local >> 9;
    int kstep = rest % ksteps, ntile = rest / ksteps;
    int quad = lane >> 4, m = lane & 15;
    int k = kstep * 32 + quad * 8 + j;
    int n = ntile * 16 + m;
    out[local] = __float2bfloat16(W[(size_t)k * N + n]);
}

// ---------------- projections via MFMA: q, k|v packed, skip(+x) ----------------
__global__ __launch_bounds__(256) void k_proj(
    const float* __restrict__ x,
    const bf16* __restrict__ wqp, const bf16* __restrict__ wkp,
    const bf16* __restrict__ wvp, const bf16* __restrict__ wskp,
    const float* __restrict__ bq, const float* __restrict__ bk,
    const float* __restrict__ bv, const float* __restrict__ bsk,
    bf16* __restrict__ qb, unsigned int* __restrict__ kvb,
    bf16* __restrict__ skipb)
{
    __shared__ __align__(16) short xs[32][136];
    __shared__ __align__(16) short os[32][520];
    const int t = threadIdx.x;
    const int wave = t >> 6, lane = t & 63;
    const int quad = lane >> 4, m = lane & 15;
    const int n0 = blockIdx.x * 32;

    for (int idx = t; idx < 32 * 32; idx += 256) {
        int row = idx >> 5, g = idx & 31;
        int node = n0 + row;
        float4 xv = {0.f, 0.f, 0.f, 0.f};
        if (node < NN) xv = *reinterpret_cast<const float4*>(&x[(size_t)node * 128 + g * 4]);
        short4 s4;
        s4.x = f2bs(xv.x); s4.y = f2bs(xv.y); s4.z = f2bs(xv.z); s4.w = f2bs(xv.w);
        *reinterpret_cast<short4*>(&xs[row][g * 4]) = s4;
    }
    __syncthreads();

    const bf16* Wp = (wave == 0) ? wqp : (wave == 1) ? wkp : (wave == 2) ? wvp : wskp;
    const float* bias = (wave == 0) ? bq : (wave == 1) ? bk : (wave == 2) ? bv : bsk;

    floatx4 acc[2][8];
#pragma unroll
    for (int mt = 0; mt < 2; ++mt)
#pragma unroll
        for (int nt = 0; nt < 8; ++nt) acc[mt][nt] = (floatx4){0.f, 0.f, 0.f, 0.f};

#pragma unroll
    for (int kstep = 0; kstep < 4; ++kstep) {
        short8 af0 = *reinterpret_cast<const short8*>(&xs[m][kstep * 32 + quad * 8]);
        short8 af1 = *reinterpret_cast<const short8*>(&xs[16 + m][kstep * 32 + quad * 8]);
#pragma unroll
        for (int nt = 0; nt < 8; ++nt) {
            short8 bf = *reinterpret_cast<const short8*>(
                reinterpret_cast<const short*>(Wp) + ((nt * 4 + kstep) * 64 + lane) * 8);
            acc[0][nt] = __builtin_amdgcn_mfma_f32_16x16x32_bf16(af0, bf, acc[0][nt], 0, 0, 0);
            acc[1][nt] = __builtin_amdgcn_mfma_f32_16x16x32_bf16(af1, bf, acc[1][nt], 0, 0, 0);
        }
    }
#pragma unroll
    for (int nt = 0; nt < 8; ++nt) {
        float bs = bias[nt * 16 + m];
#pragma unroll
        for (int mt = 0; mt < 2; ++mt)
#pragma unroll
            for (int r = 0; r < 4; ++r)
                os[mt * 16 + quad * 4 + r][wave * 128 + nt * 16 + m] = f2bs(acc[mt][nt][r] + bs);
    }
    __syncthreads();
    // output: q (bf16), skip+x (bf16), kv packed as uint (k low16 | v high16)
    for (int idx = t; idx < 32 * 64; idx += 256) {
        int row = idx >> 6, c = idx & 63;
        int node = n0 + row;
        if (node >= NN) continue;
        unsigned int qu  = *reinterpret_cast<const unsigned int*>(&os[row][2 * c]);
        unsigned int ku  = *reinterpret_cast<const unsigned int*>(&os[row][128 + 2 * c]);
        unsigned int vu  = *reinterpret_cast<const unsigned int*>(&os[row][256 + 2 * c]);
        float sk0 = bs2f(os[row][384 + 2 * c])     + bs2f(xs[row][2 * c]);
        float sk1 = bs2f(os[row][384 + 2 * c + 1]) + bs2f(xs[row][2 * c + 1]);
        unsigned int sku = (unsigned int)(unsigned short)f2bs(sk0) |
                           ((unsigned int)(unsigned short)f2bs(sk1) << 16);
        reinterpret_cast<unsigned int*>(qb)[(size_t)node * 64 + c] = qu;
        reinterpret_cast<unsigned int*>(skipb)[(size_t)node * 64 + c] = sku;
        uint2 kv;
        kv.x = (ku & 0xffffu) | (vu << 16);          // ch 2c  : k|v
        kv.y = (ku >> 16) | (vu & 0xffff0000u);      // ch 2c+1: k|v
        reinterpret_cast<uint2*>(kvb)[(size_t)node * 64 + c] = kv;
    }
}

// ---------------- CSR build ----------------
// hist: atomicAdd returns the within-node RANK — save it (+ src/dst as int32)
// so k_scatter needs no second atomic pass and no int64 re-read.
__global__ void k_hist(const int* __restrict__ ei, const int* __restrict__ flag,
                       int* __restrict__ deg, int* __restrict__ rankb,
                       int* __restrict__ dstc, int* __restrict__ srcc)
{
    int tt = blockIdx.x * 256 + threadIdx.x;
    int i0 = tt * 2;
    if (i0 >= EE) return;
    int d0, d1, s0, s1;
    if (flag[0]) {
        int4 dv = *reinterpret_cast<const int4*>(&ei[2 * EE + 2 * i0]);
        int4 sv = *reinterpret_cast<const int4*>(&ei[2 * i0]);
        d0 = dv.x; d1 = dv.z; s0 = sv.x; s1 = sv.z;
    } else {
        int2 dv = *reinterpret_cast<const int2*>(&ei[EE + i0]);
        int2 sv = *reinterpret_cast<const int2*>(&ei[i0]);
        d0 = dv.x; d1 = dv.y; s0 = sv.x; s1 = sv.y;
    }
    d0 = clampn(d0); d1 = clampn(d1);
    int r0 = atomicAdd(&deg[d0], 1);
    int r1 = atomicAdd(&deg[d1], 1);
    *reinterpret_cast<int2*>(&rankb[i0]) = make_int2(r0, r1);
    *reinterpret_cast<int2*>(&dstc[i0])  = make_int2(d0, d1);
    *reinterpret_cast<int2*>(&srcc[i0])  = make_int2(clampn(s0), clampn(s1));
}

__global__ __launch_bounds__(1024) void k_scan(const int* __restrict__ deg,
                                               int* __restrict__ rowstart)
{
    __shared__ int s[1024];
    const int t = threadIdx.x;
    const int CH = 49;
    int base = t * CH;
    int sum = 0;
    for (int i = 0; i < CH; i++) {
        int idx = base + i;
        if (idx < NN) sum += deg[idx];
    }
    s[t] = sum;
    __syncthreads();
    int own = sum;
    for (int off = 1; off < 1024; off <<= 1) {
        int v = (t >= off) ? s[t - off] : 0;
        __syncthreads();
        s[t] += v;
        __syncthreads();
    }
    int run = s[t] - own;
    for (int i = 0; i < CH; i++) {
        int idx = base + i;
        if (idx < NN) {
            rowstart[idx] = run;
            run += deg[idx];
        }
    }
    if (t == 0) rowstart[NN] = EE;
}

// scatter: atomic-free — pos = rowstart[dst] + rank; pure streaming reads
__global__ void k_scatter(const int* __restrict__ rankb, const int* __restrict__ dstc,
                          const int* __restrict__ srcc,
                          const int* __restrict__ rowstart, int2* __restrict__ srcid)
{
    int tt = blockIdx.x * 256 + threadIdx.x;
    int i0 = tt * 2;
    if (i0 >= EE) return;
    int2 r = *reinterpret_cast<const int2*>(&rankb[i0]);
    int2 d = *reinterpret_cast<const int2*>(&dstc[i0]);
    int2 s = *reinterpret_cast<const int2*>(&srcc[i0]);
    srcid[rowstart[d.x] + r.x] = make_int2(s.x, i0);
    srcid[rowstart[d.y] + r.y] = make_int2(s.y, i0 + 1);
}

// -------- fused attention: PERSISTENT WAVES, 64 partitioned queue counters --------
// block = 256 threads = 4 waves; wave g pops node batches (4) from counter g&63.
// lane owns channels 2*lane, 2*lane+1 (head = lane>>3, 8 lanes per head).
// A-frag read directly from edge_attr (fp32, full-line random reads).
__global__ __launch_bounds__(256) void k_attn(
    const float* __restrict__ edge_attr, const bf16* __restrict__ wep,
    const bf16* __restrict__ qb, const unsigned int* __restrict__ kvb,
    const bf16* __restrict__ skipb,
    const int* __restrict__ rowstart, const int2* __restrict__ srcid,
    const float* __restrict__ ln1g, const float* __restrict__ ln1b,
    int* __restrict__ qcounter, bf16* __restrict__ hb)
{
    // es transposed: [channel][edge] with stride 18 shorts (36B) per channel row
    __shared__ __align__(16) short es[4][128][18];
    __shared__ __align__(16) short wes[4096];
    const int t = threadIdx.x;
    const int wave = t >> 6, lane = t & 63;
    const int quad = lane >> 4, m = lane & 15;

    // stage We fragments once per block (8 ntiles x 64 lanes x 8 bf16 = 8KB)
    for (int idx = t; idx < 512; idx += 256)
        *reinterpret_cast<short8*>(&wes[idx * 8]) =
            *reinterpret_cast<const short8*>(reinterpret_cast<const short*>(wep) + idx * 8);
    __syncthreads();   // only barrier in the kernel

    short (*esw)[18] = es[wave];
    const float QS = 0.3606737602f;   // 0.25 * log2(e)

    const int gw = blockIdx.x * 4 + wave;
    const int c  = gw & (NQC - 1);
    const int base = c * PART;
    const int cnt_c = (NN - base < PART) ? (NN - base) : PART;
    int* qc = qcounter + c * 16;   // 64B stride: one counter per cacheline

    for (;;) {
        int nl;
        if (lane == 0) nl = atomicAdd(qc, 4);
        nl = __builtin_amdgcn_readfirstlane(nl);
        if (nl >= cnt_c) break;
        const int nhi = (nl + 4 < cnt_c) ? nl + 4 : cnt_c;

        for (int ni = nl; ni < nhi; ++ni) {
            const int n = base + ni;

            unsigned int qp = reinterpret_cast<const unsigned int*>(qb)[(size_t)n * 64 + lane];
            float q0 = bu2f((unsigned short)(qp & 0xffffu)) * QS;
            float q1 = bu2f((unsigned short)(qp >> 16)) * QS;

            const int eoff = rowstart[n], eend = rowstart[n + 1];
            float lsum = 0.f, acc0 = 0.f, acc1 = 0.f;

            for (int p0 = eoff; p0 < eend; p0 += 16) {
                int pos = p0 + m;
                int pc = (pos < eend) ? pos : eoff;
                int2 se = srcid[pc];   // lane m holds {src, eid} for tile edge m

                // A-frag: direct fp32 loads from edge_attr (full lines, 4 quads)
                const float* arow = edge_attr + (size_t)se.y * 32 + quad * 8;
                float4 a0 = *reinterpret_cast<const float4*>(arow);
                float4 a1 = *reinterpret_cast<const float4*>(arow + 4);

                // kv prefetch: 16 coalesced 8B loads, SGPR row base via readlane
                uint2 kvr[16];
#pragma unroll
                for (int j = 0; j < 16; ++j) {
                    int sj = __builtin_amdgcn_readlane(se.x, j);
                    kvr[j] = reinterpret_cast<const uint2*>(kvb + (size_t)(unsigned)sj * 128)[lane];
                }

                short8 Af;
                Af[0] = f2bs(a0.x); Af[1] = f2bs(a0.y); Af[2] = f2bs(a0.z); Af[3] = f2bs(a0.w);
                Af[4] = f2bs(a1.x); Af[5] = f2bs(a1.y); Af[6] = f2bs(a1.z); Af[7] = f2bs(a1.w);
#pragma unroll
                for (int nt = 0; nt < 8; ++nt) {
                    short8 Bf = *reinterpret_cast<const short8*>(&wes[(nt * 64 + lane) * 8]);
                    floatx4 C = {0.f, 0.f, 0.f, 0.f};
                    C = __builtin_amdgcn_mfma_f32_16x16x32_bf16(Af, Bf, C, 0, 0, 0);
                    int col = nt * 16 + m;
                    unsigned int d0 = (unsigned int)(unsigned short)f2bs(C[0]) |
                                      ((unsigned int)(unsigned short)f2bs(C[1]) << 16);
                    unsigned int d1 = (unsigned int)(unsigned short)f2bs(C[2]) |
                                      ((unsigned int)(unsigned short)f2bs(C[3]) << 16);
                    unsigned int* p = reinterpret_cast<unsigned int*>(&esw[col][quad * 4]);
                    p[0] = d0; p[1] = d1;   // edges quad*4..quad*4+3 of channel col
                }
                __builtin_amdgcn_wave_barrier();   // wave-local LDS: writes before reads

                // batch-read e for this lane's 2 channels, all 16 edges -> registers
                unsigned int ear[8], ebr[8];
                {
                    const unsigned int* ra = reinterpret_cast<const unsigned int*>(&esw[2 * lane][0]);
                    const unsigned int* rb = reinterpret_cast<const unsigned int*>(&esw[2 * lane + 1][0]);
#pragma unroll
                    for (int jj = 0; jj < 8; ++jj) { ear[jj] = ra[jj]; ebr[jj] = rb[jj]; }
                }

                int cnt = eend - p0; if (cnt > 16) cnt = 16;
#pragma unroll
                for (int j = 0; j < 16; ++j) {
                    unsigned int eva = ear[j >> 1], evb = ebr[j >> 1];
                    float e0 = (j & 1) ? bu2f((unsigned short)(eva >> 16))
                                       : bu2f((unsigned short)(eva & 0xffffu));
                    float e1 = (j & 1) ? bu2f((unsigned short)(evb >> 16))
                                       : bu2f((unsigned short)(evb & 0xffffu));
                    float k0 = bu2f((unsigned short)(kvr[j].x & 0xffffu));
                    float v0 = bu2f((unsigned short)(kvr[j].x >> 16));
                    float k1 = bu2f((unsigned short)(kvr[j].y & 0xffffu));
                    float v1 = bu2f((unsigned short)(kvr[j].y >> 16));
                    float pr = fmaf(k1 + e1, q1, (k0 + e0) * q0);   // pre-scaled by 0.25*log2e
                    // 3-level xor butterfly over the 8-lane head group (BitMode swizzle)
                    pr += __int_as_float(__builtin_amdgcn_ds_swizzle(__float_as_int(pr), 0x041F));
                    pr += __int_as_float(__builtin_amdgcn_ds_swizzle(__float_as_int(pr), 0x081F));
                    pr += __int_as_float(__builtin_amdgcn_ds_swizzle(__float_as_int(pr), 0x101F));
                    float w = (j < cnt) ? __builtin_amdgcn_exp2f(pr) : 0.f;
                    lsum += w;
                    acc0 = fmaf(v0 + e0, w, acc0);
                    acc1 = fmaf(v1 + e1, w, acc1);
                }
                __builtin_amdgcn_wave_barrier();   // reads before next tile's writes
            }

            float rden = 1.f / (lsum + 1e-16f);
            float attn0 = acc0 * rden, attn1 = acc1 * rden;
            unsigned int skp = reinterpret_cast<const unsigned int*>(skipb)[(size_t)n * 64 + lane];
            float pre0 = attn0 + bu2f((unsigned short)(skp & 0xffffu));   // skipb = skip + x
            float pre1 = attn1 + bu2f((unsigned short)(skp >> 16));
            float s1 = pre0 + pre1, s2 = pre0 * pre0 + pre1 * pre1;
#pragma unroll
            for (int off = 1; off < 64; off <<= 1) {
                s1 += __shfl_xor(s1, off);
                s2 += __shfl_xor(s2, off);
            }
            float mu = s1 * (1.f / 128.f);
            float var = s2 * (1.f / 128.f) - mu * mu;
            float inv = rsqrtf(var + 1e-5f);
            float2 g  = *reinterpret_cast<const float2*>(ln1g + 2 * lane);
            float2 bb = *reinterpret_cast<const float2*>(ln1b + 2 * lane);
            float h0 = (pre0 - mu) * inv * g.x + bb.x;
            float h1 = (pre1 - mu) * inv * g.y + bb.y;
            unsigned int hu = (unsigned int)(unsigned short)f2bs(h0) |
                              ((unsigned int)(unsigned short)f2bs(h1) << 16);
            reinterpret_cast<unsigned int*>(hb)[(size_t)n * 64 + lane] = hu;
        }
    }
}

// ---------------- FFN via MFMA + LN2 ----------------
__global__ __launch_bounds__(256) void k_ffn(
    const bf16* __restrict__ hb,
    const bf16* __restrict__ w1p, const float* __restrict__ b1,
    const bf16* __restrict__ w2p, const float* __restrict__ b2,
    const float* __restrict__ ln2g, const float* __restrict__ ln2b,
    float* __restrict__ out)
{
    __shared__ __align__(16) short hs[32][136];
    __shared__ __align__(16) short t1s[32][520];
    float* fs = reinterpret_cast<float*>(&t1s[0][0]);  // [32][132] after t1s is dead
    const int t = threadIdx.x;
    const int wave = t >> 6, lane = t & 63;
    const int quad = lane >> 4, m = lane & 15;
    const int n0 = blockIdx.x * 32;

    for (int idx = t; idx < 32 * 16; idx += 256) {
        int row = idx >> 4, g = idx & 15;
        int node = n0 + row;
        if (node < NN) {
            *reinterpret_cast<float4*>(&hs[row][g * 8]) =
                *reinterpret_cast<const float4*>(&hb[(size_t)node * 128 + g * 8]);
        } else {
            float4 z = {0.f, 0.f, 0.f, 0.f};
            *reinterpret_cast<float4*>(&hs[row][g * 8]) = z;
        }
    }
    __syncthreads();

    floatx4 acc1[2][8];
#pragma unroll
    for (int mt = 0; mt < 2; ++mt)
#pragma unroll
        for (int nt = 0; nt < 8; ++nt) acc1[mt][nt] = (floatx4){0.f, 0.f, 0.f, 0.f};
#pragma unroll
    for (int kstep = 0; kstep < 4; ++kstep) {
        short8 af0 = *reinterpret_cast<const short8*>(&hs[m][kstep * 32 + quad * 8]);
        short8 af1 = *reinterpret_cast<const short8*>(&hs[16 + m][kstep * 32 + quad * 8]);
#pragma unroll
        for (int nt = 0; nt < 8; ++nt) {
            short8 bf = *reinterpret_cast<const short8*>(
                reinterpret_cast<const short*>(w1p) + (((wave * 8 + nt) * 4 + kstep) * 64 + lane) * 8);
            acc1[0][nt] = __builtin_amdgcn_mfma_f32_16x16x32_bf16(af0, bf, acc1[0][nt], 0, 0, 0);
            acc1[1][nt] = __builtin_amdgcn_mfma_f32_16x16x32_bf16(af1, bf, acc1[1][nt], 0, 0, 0);
        }
    }
#pragma unroll
    for (int nt = 0; nt < 8; ++nt) {
        float bs = b1[wave * 128 + nt * 16 + m];
#pragma unroll
        for (int mt = 0; mt < 2; ++mt)
#pragma unroll
            for (int r = 0; r < 4; ++r)
                t1s[mt * 16 + quad * 4 + r][wave * 128 + nt * 16 + m] =
                    f2bs(fmaxf(acc1[mt][nt][r] + bs, 0.f));
    }
    __syncthreads();

    floatx4 acc2[2][2];
#pragma unroll
    for (int mt = 0; mt < 2; ++mt)
#pragma unroll
        for (int nt = 0; nt < 2; ++nt) acc2[mt][nt] = (floatx4){0.f, 0.f, 0.f, 0.f};
#pragma unroll
    for (int kstep = 0; kstep < 16; ++kstep) {
        short8 af0 = *reinterpret_cast<const short8*>(&t1s[m][kstep * 32 + quad * 8]);
        short8 af1 = *reinterpret_cast<const short8*>(&t1s[16 + m][kstep * 32 + quad * 8]);
#pragma unroll
        for (int nt = 0; nt < 2; ++nt) {
            short8 bf = *reinterpret_cast<const short8*>(
                reinterpret_cast<const short*>(w2p) + (((wave * 2 + nt) * 16 + kstep) * 64 + lane) * 8);
            acc2[0][nt] = __builtin_amdgcn_mfma_f32_16x16x32_bf16(af0, bf, acc2[0][nt], 0, 0, 0);
            acc2[1][nt] = __builtin_amdgcn_mfma_f32_16x16x32_bf16(af1, bf, acc2[1][nt], 0, 0, 0);
        }
    }
    __syncthreads();
#pragma unroll
    for (int nt = 0; nt < 2; ++nt) {
        int col = (wave * 2 + nt) * 16 + m;
        float bs = b2[col];
#pragma unroll
        for (int mt = 0; mt < 2; ++mt)
#pragma unroll
            for (int r = 0; r < 4; ++r)
                fs[(mt * 16 + quad * 4 + r) * 132 + col] = acc2[mt][nt][r] + bs;
    }
    __syncthreads();

    for (int rr = 0; rr < 8; ++rr) {
        int row = wave * 8 + rr;
        int node = n0 + row;
        float p0 = bs2f(hs[row][lane]) + fs[row * 132 + lane];
        float p1 = bs2f(hs[row][lane + 64]) + fs[row * 132 + lane + 64];
        float s1 = p0 + p1, s2 = p0 * p0 + p1 * p1;
#pragma unroll
        for (int off = 1; off < 64; off <<= 1) {
            s1 += __shfl_xor(s1, off);
            s2 += __shfl_xor(s2, off);
        }
        float mu = s1 * (1.f / 128.f);
        float var = s2 * (1.f / 128.f) - mu * mu;
        float inv = rsqrtf(var + 1e-5f);
        if (node < NN) {
            out[(size_t)node * 128 + lane] = (p0 - mu) * inv * ln2g[lane] + ln2b[lane];
            out[(size_t)node * 128 + lane + 64] = (p1 - mu) * inv * ln2g[lane + 64] + ln2b[lane + 64];
        }
    }
}

extern "C" void kernel_launch(void* const* d_in, const int* in_sizes, int n_in,
                              void* d_out, int out_size, void* d_ws, size_t ws_size,
                              hipStream_t stream)
{
    const float* x    = (const float*)d_in[0];
    const int*   ei   = (const int*)d_in[1];
    const float* ea   = (const float*)d_in[2];
    const float* Wq   = (const float*)d_in[3];
    const float* bq   = (const float*)d_in[4];
    const float* Wk   = (const float*)d_in[5];
    const float* bk   = (const float*)d_in[6];
    const float* Wv   = (const float*)d_in[7];
    const float* bv   = (const float*)d_in[8];
    const float* We   = (const float*)d_in[9];
    const float* Wsk  = (const float*)d_in[10];
    const float* bsk  = (const float*)d_in[11];
    const float* ln1g = (const float*)d_in[12];
    const float* ln1b = (const float*)d_in[13];
    const float* W1   = (const float*)d_in[14];
    const float* b1   = (const float*)d_in[15];
    const float* W2   = (const float*)d_in[16];
    const float* b2   = (const float*)d_in[17];
    const float* ln2g = (const float*)d_in[18];
    const float* ln2b = (const float*)d_in[19];

    char* ws = (char*)d_ws;
    size_t off = 0;
    auto alloc = [&](size_t bytes) -> void* {
        void* p = ws + off;
        off += (bytes + 255) & ~(size_t)255;
        return p;
    };
    int*   flag     = (int*)alloc(256);
    int*   qcounter = (int*)alloc((size_t)NQC * 16 * 4);   // 64 counters, 64B stride
    int*   deg      = (int*)alloc((size_t)NN * 4);
    int*   rowstart = (int*)alloc((size_t)(NN + 1) * 4);
    int*   rankb    = (int*)alloc((size_t)EE * 4);
    int*   dstc     = (int*)alloc((size_t)EE * 4);
    int*   srcc     = (int*)alloc((size_t)EE * 4);
    int2*  srcid    = (int2*)alloc((size_t)EE * 8);
    bf16*  qb       = (bf16*)alloc((size_t)NN * 128 * 2);
    unsigned int* kvb = (unsigned int*)alloc((size_t)NN * 128 * 4);
    bf16*  skipb    = (bf16*)alloc((size_t)NN * 128 * 2);
    bf16*  hb       = (bf16*)alloc((size_t)NN * 128 * 2);
    bf16*  wqp      = (bf16*)alloc((size_t)16384 * 2);
    bf16*  wkp      = (bf16*)alloc((size_t)16384 * 2);
    bf16*  wvp      = (bf16*)alloc((size_t)16384 * 2);
    bf16*  wskp     = (bf16*)alloc((size_t)16384 * 2);
    bf16*  w1p      = (bf16*)alloc((size_t)65536 * 2);
    bf16*  w2p      = (bf16*)alloc((size_t)65536 * 2);
    bf16*  wep      = (bf16*)alloc((size_t)4096 * 2);

    k_packall<<<785, 256, 0, stream>>>(
        Wq, Wk, Wv, Wsk, W1, W2, We, wqp, wkp, wvp, wskp, w1p, w2p, wep,
        ei, flag, deg, qcounter);
    k_hist<<<(EE / 2 + 255) / 256, 256, 0, stream>>>(ei, flag, deg, rankb, dstc, srcc);
    k_proj<<<(NN + 31) / 32, 256, 0, stream>>>(x, wqp, wkp, wvp, wskp,
                                               bq, bk, bv, bsk, qb, kvb, skipb);
    k_scan<<<1, 1024, 0, stream>>>(deg, rowstart);
    k_scatter<<<(EE / 2 + 255) / 256, 256, 0, stream>>>(rankb, dstc, srcc,
                                                        rowstart, srcid);
    k_attn<<<1536, 256, 0, stream>>>(ea, wep, qb, kvb, skipb,
                                     rowstart, srcid, ln1g, ln1b, qcounter, hb);
    k_ffn<<<(NN + 31) / 32, 256, 0, stream>>>(hb, w1p, b1, w2p, b2, ln2g, ln2b, (float*)d_out);
}